// Round 11
// baseline (1092.036 us; speedup 1.0000x reference)
//
#include <hip/hip_runtime.h>
#include <hip/hip_bf16.h>
#include <math.h>

#define N_NODES   100000
#define N_EDGES   1600000
#define N_GRAPHS  64
#define NF_D      140
#define OP_EMB_D  32
#define CFG_D     18
#define K_EMB     192     // 190 zero-padded to 192
#define NB_SCAN   391     // ceil(N_NODES/256)

// monotone float<->uint encoding for atomicMax on floats
__device__ __forceinline__ unsigned fenc(float f) {
    unsigned u = __float_as_uint(f);
    return (u & 0x80000000u) ? ~u : (u | 0x80000000u);
}
__device__ __forceinline__ float fdec(unsigned u) {
    unsigned v = (u & 0x80000000u) ? (u & 0x7FFFFFFFu) : ~u;
    return __uint_as_float(v);
}
// self-contained bf16 pack/unpack (RNE; finite inputs only)
__device__ __forceinline__ unsigned short f2bf(float f) {
    unsigned u = __float_as_uint(f);
    return (unsigned short)((u + 0x7FFFu + ((u >> 16) & 1u)) >> 16);
}
__device__ __forceinline__ float bf2f(unsigned short h) {
    return __uint_as_float((unsigned)h << 16);
}

// ---------------- CSR build ----------------

__global__ void hist_kernel(const int* __restrict__ dst, int* __restrict__ cnt) {
    int e = blockIdx.x * blockDim.x + threadIdx.x;
    if (e < N_EDGES) atomicAdd(&cnt[dst[e]], 1);
}

__global__ __launch_bounds__(256) void blocksum_kernel(const int* __restrict__ cnt,
                                                       int* __restrict__ bsum) {
    const int tid = threadIdx.x, lane = tid & 63, wave = tid >> 6;
    int i = blockIdx.x * 256 + tid;
    int v = (i < N_NODES) ? cnt[i] : 0;
    #pragma unroll
    for (int off = 32; off > 0; off >>= 1) v += __shfl_xor(v, off, 64);
    __shared__ int wsum[4];
    if (lane == 0) wsum[wave] = v;
    __syncthreads();
    if (tid == 0) bsum[blockIdx.x] = wsum[0] + wsum[1] + wsum[2] + wsum[3];
}

__global__ __launch_bounds__(512) void scanbsum_kernel(int* __restrict__ bsum) {
    __shared__ int s[512];
    const int t = threadIdx.x;
    int v0 = (t < NB_SCAN) ? bsum[t] : 0;
    s[t] = v0;
    __syncthreads();
    for (int off = 1; off < 512; off <<= 1) {
        int add = (t >= off) ? s[t - off] : 0;
        __syncthreads();
        s[t] += add;
        __syncthreads();
    }
    if (t < NB_SCAN) bsum[t] = s[t] - v0;   // exclusive
}

__global__ __launch_bounds__(256) void offsets_kernel(int* __restrict__ cnt,
                                                      const int* __restrict__ bsum,
                                                      int* __restrict__ row_start) {
    const int t = threadIdx.x;
    const int i = blockIdx.x * 256 + t;
    int v0 = (i < N_NODES) ? cnt[i] : 0;
    __shared__ int s[256];
    s[t] = v0;
    __syncthreads();
    for (int off = 1; off < 256; off <<= 1) {
        int add = (t >= off) ? s[t - off] : 0;
        __syncthreads();
        s[t] += add;
        __syncthreads();
    }
    const int excl = s[t] - v0 + bsum[blockIdx.x];
    if (i < N_NODES) {
        row_start[i] = excl;
        cnt[i] = excl;                 // becomes the fill cursor
    }
    if (i == N_NODES - 1) row_start[N_NODES] = excl + v0;  // == N_EDGES
}

// range-partitioned fill (R7: random scatter caused 16x write amp; this keeps
// each 0.8MB nbr slice hot in one XCD L2 via the blockIdx%8 heuristic).
__global__ void fill_kernel(const int* __restrict__ src, const int* __restrict__ dst,
                            int* __restrict__ cursor, int* __restrict__ nbr) {
    const int range = blockIdx.x & 7;
    const int lo = range * (N_NODES / 8);
    const int hi = lo + (N_NODES / 8);
    const int groups = gridDim.x >> 3;
    const int sub = blockIdx.x >> 3;
    for (int e = sub * blockDim.x + threadIdx.x; e < N_EDGES;
         e += groups * blockDim.x) {
        const int d = dst[e];
        if (d >= lo && d < hi) {
            const int slot = atomicAdd(&cursor[d], 1);
            nbr[slot] = src[e];
        }
    }
}

// ---------------- input concat (bf16 out) + weight pad ----------------

__global__ __launch_bounds__(256) void concat_kernel(
    const float* __restrict__ node_feat, const float* __restrict__ cfg,
    const int* __restrict__ opcode, const float* __restrict__ op_emb,
    unsigned short* __restrict__ x0)
{
    const long long total = (long long)N_NODES * 96;   // 2-col units
    for (long long idx = (long long)blockIdx.x * blockDim.x + threadIdx.x;
         idx < total; idx += (long long)gridDim.x * blockDim.x) {
        const int n  = (int)(idx / 96);
        const int c  = 2 * (int)(idx % 96);
        float2 v;
        if (c < NF_D) {
            v = *(const float2*)(node_feat + (long long)n * NF_D + c);
        } else if (c < NF_D + OP_EMB_D) {
            const int op = opcode[n];
            v = *(const float2*)(op_emb + op * OP_EMB_D + (c - NF_D));
        } else if (c < 190) {
            v = *(const float2*)(cfg + (long long)n * CFG_D + (c - NF_D - OP_EMB_D));
        } else {
            v.x = 0.f; v.y = 0.f;
        }
        const unsigned pk = ((unsigned)f2bf(v.y) << 16) | (unsigned)f2bf(v.x);
        *(unsigned*)(x0 + (long long)n * K_EMB + c) = pk;
    }
}

__global__ void wpad_kernel(const float* __restrict__ w, float* __restrict__ wp) {
    int i = blockIdx.x * blockDim.x + threadIdx.x;
    if (i < K_EMB * 128) wp[i] = (i < 190 * 128) ? w[i] : 0.f;
}

// ---------------- lane-per-node GEMM (wave-local staging, NO barriers — R9 lesson) ----------------
// wave = 64-node tile, lane = node. blockIdx.y = JW-col output tile (JW=64:
// halves input re-fetch vs JW=32; VGPR ~100 still >= the 4-waves/SIMD LDS cap).
// IBF16: bf16 input rows staged via uint4 + register unpack into fp32 LDS.
// OBF16: bf16 output rows. Weights fp32, wave-uniform -> s_load. acc[JW]/lane.
template <int M, int JW, bool BIAS, bool RELU, bool OBF16, bool IBF16>
__global__ __launch_bounds__(256) void gemm_kernel(
    const void* __restrict__ xin, int SX, int K,
    const float* __restrict__ w, const float* __restrict__ b,
    void* __restrict__ outv, int N)
{
    __shared__ float sx[4][64][36];
    const int tid = threadIdx.x, wave = tid >> 6, lane = tid & 63;
    const int jh = blockIdx.y;
    const int ntiles = (N + 63) >> 6;
    for (int tile = blockIdx.x * 4 + wave; tile < ntiles; tile += gridDim.x * 4) {
        const int base = tile << 6;
        float acc[JW];
        #pragma unroll
        for (int j = 0; j < JW; ++j) acc[j] = BIAS ? b[jh * JW + j] : 0.f;
        for (int kc = 0; kc < K; kc += 32) {
            if (IBF16) {
                const unsigned short* x = (const unsigned short*)xin;
                const int r16 = lane >> 2, c2 = lane & 3;   // 16 rows x 4 uint4 per pass
                #pragma unroll
                for (int rt = 0; rt < 4; ++rt) {
                    int row = base + rt * 16 + r16;
                    if (row >= N) row = N - 1;
                    uint4 u = *(const uint4*)(x + (long long)row * SX + kc + c2 * 8);
                    float4 lo, hi;
                    lo.x = __uint_as_float(u.x << 16);
                    lo.y = __uint_as_float(u.x & 0xffff0000u);
                    lo.z = __uint_as_float(u.y << 16);
                    lo.w = __uint_as_float(u.y & 0xffff0000u);
                    hi.x = __uint_as_float(u.z << 16);
                    hi.y = __uint_as_float(u.z & 0xffff0000u);
                    hi.z = __uint_as_float(u.w << 16);
                    hi.w = __uint_as_float(u.w & 0xffff0000u);
                    *(float4*)(&sx[wave][rt * 16 + r16][c2 * 8 + 0]) = lo;
                    *(float4*)(&sx[wave][rt * 16 + r16][c2 * 8 + 4]) = hi;
                }
            } else {
                const float* x = (const float*)xin;
                const int r8 = lane >> 3, c4 = lane & 7;    // 8 rows x 8 float4 per pass
                #pragma unroll
                for (int rt = 0; rt < 8; ++rt) {
                    int row = base + rt * 8 + r8;
                    if (row >= N) row = N - 1;
                    float4 v = *(const float4*)(x + (long long)row * SX + kc + c4 * 4);
                    *(float4*)(&sx[wave][rt * 8 + r8][c4 * 4]) = v;
                }
            }
            // wave-local staging: in-order DS pipe + compiler waitcnt suffice
            #pragma unroll 2
            for (int i4 = 0; i4 < 8; ++i4) {
                float4 xv = *(const float4*)(&sx[wave][lane][i4 * 4]);
                const float* wrow = w + (long long)(kc + i4 * 4) * M + jh * JW;
                #pragma unroll
                for (int q = 0; q < 4; ++q) {
                    const float xq = (q == 0) ? xv.x : (q == 1) ? xv.y
                                   : (q == 2) ? xv.z : xv.w;
                    #pragma unroll
                    for (int j = 0; j < JW; ++j)
                        acc[j] = fmaf(xq, wrow[q * M + j], acc[j]);
                }
            }
        }
        const int n = base + lane;
        if (n < N) {
            if (OBF16) {
                unsigned short* orow = (unsigned short*)outv + (long long)n * M + jh * JW;
                #pragma unroll
                for (int j8 = 0; j8 < JW / 8; ++j8) {
                    uint4 pk;
                    unsigned* pu = (unsigned*)&pk;
                    #pragma unroll
                    for (int h = 0; h < 4; ++h) {
                        float f0 = acc[j8 * 8 + h * 2], f1 = acc[j8 * 8 + h * 2 + 1];
                        if (RELU) { f0 = fmaxf(f0, 0.f); f1 = fmaxf(f1, 0.f); }
                        pu[h] = ((unsigned)f2bf(f1) << 16) | (unsigned)f2bf(f0);
                    }
                    *(uint4*)(orow + j8 * 8) = pk;
                }
            } else {
                float* orow = (float*)outv + (long long)n * M + jh * JW;
                #pragma unroll
                for (int j4 = 0; j4 < JW / 4; ++j4) {
                    float4 v;
                    v.x = acc[j4 * 4 + 0]; v.y = acc[j4 * 4 + 1];
                    v.z = acc[j4 * 4 + 2]; v.w = acc[j4 * 4 + 3];
                    if (RELU) {
                        v.x = fmaxf(v.x, 0.f); v.y = fmaxf(v.y, 0.f);
                        v.z = fmaxf(v.z, 0.f); v.w = fmaxf(v.w, 0.f);
                    }
                    *(float4*)(orow + j4 * 4) = v;
                }
            }
        }
    }
}

// ---------------- gather + normalize (root term precomputed as r) ----------------
// out[n] = normalize( gather_mean(yp)[n] + r[n] ),  r = x@wr + bl (dense GEMM)
// yp bf16; fp32 accumulate. 8 waves/SIMD; 8 independent gather accumulators.
// OBF16: write the normalized output as bf16 (C1/C2 are re-read twice by GEMMs).
template <bool OBF16>
__global__ __launch_bounds__(256, 8) void combine_kernel(
    const int* __restrict__ row_start, const int* __restrict__ nbr,
    const unsigned short* __restrict__ yp, const float* __restrict__ r,
    void* __restrict__ out)
{
    const int tid = threadIdx.x, wave = tid >> 6, lane = tid & 63;
    for (int n = blockIdx.x * 4 + wave; n < N_NODES; n += gridDim.x * 4) {
        const int rs = row_start[n], re = row_start[n + 1];
        float macc[8];
        #pragma unroll
        for (int q = 0; q < 8; ++q) macc[q] = 0.f;
        for (int eb = rs; eb < re; eb += 64) {
            const int cnt = min(64, re - eb);
            const int my = (eb + lane < re) ? nbr[eb + lane] : 0;
            for (int j2 = 0; j2 < cnt; j2 += 8) {
                #pragma unroll
                for (int q = 0; q < 8; ++q) {
                    const int jj = j2 + q;                       // wave-uniform
                    const int s = __shfl(my, (jj < cnt) ? jj : 0, 64);
                    const float v = bf2f(yp[(long long)s * 64 + lane]);
                    if (jj < cnt) macc[q] += v;                  // uniform predicate
                }
            }
        }
        const float m = ((macc[0] + macc[1]) + (macc[2] + macc[3]))
                      + ((macc[4] + macc[5]) + (macc[6] + macc[7]));
        float acc = r[(long long)n * 64 + lane] + m / fmaxf((float)(re - rs), 1.0f);
        float sq = acc * acc;
        #pragma unroll
        for (int off = 32; off > 0; off >>= 1) sq += __shfl_xor(sq, off, 64);
        const float res = acc / fmaxf(sqrtf(sq), 1e-12f);
        if (OBF16)
            ((unsigned short*)out)[(long long)n * 64 + lane] = f2bf(res);
        else
            ((float*)out)[(long long)n * 64 + lane] = res;
    }
}

// ---------------- pooling (block pre-reduction) + head ----------------

__global__ __launch_bounds__(256) void pool_kernel(
    const float* __restrict__ x, const int* __restrict__ batch,
    float* __restrict__ gsum, unsigned* __restrict__ gmax, float* __restrict__ gcnt)
{
    __shared__ float    lsum[2][64];
    __shared__ unsigned lmax[2][64];
    __shared__ int      lcnt[2];
    const int tid = threadIdx.x, wave = tid >> 6, lane = tid & 63;
    if (tid < 128) { lsum[tid >> 6][tid & 63] = 0.f; lmax[tid >> 6][tid & 63] = 0u; }
    if (tid < 2) lcnt[tid] = 0;
    __syncthreads();
    const int base = blockIdx.x * 256;
    const int g0 = batch[base];
    float a0 = 0.f, a1 = 0.f, x0 = -INFINITY, x1 = -INFINITY;
    int c0 = 0, c1 = 0;
    for (int nn = 0; nn < 64; ++nn) {
        const int n = base + wave * 64 + nn;
        if (n >= N_NODES) break;
        const float v = x[(long long)n * 64 + lane];
        const int slot = batch[n] - g0;
        if (slot == 0)      { a0 += v; x0 = fmaxf(x0, v); c0++; }
        else if (slot == 1) { a1 += v; x1 = fmaxf(x1, v); c1++; }
        else {
            const int g = g0 + slot;
            atomicAdd(&gsum[g * 64 + lane], v);
            atomicMax(&gmax[g * 64 + lane], fenc(v));
            if (lane == 0) atomicAdd(&gcnt[g], 1.f);
        }
    }
    if (c0) { atomicAdd(&lsum[0][lane], a0); atomicMax(&lmax[0][lane], fenc(x0));
              if (lane == 0) atomicAdd(&lcnt[0], c0); }
    if (c1) { atomicAdd(&lsum[1][lane], a1); atomicMax(&lmax[1][lane], fenc(x1));
              if (lane == 0) atomicAdd(&lcnt[1], c1); }
    __syncthreads();
    if (tid < 128) {
        const int slot = tid >> 6, k = tid & 63;
        if (lcnt[slot] > 0) {
            const int g = g0 + slot;
            atomicAdd(&gsum[g * 64 + k], lsum[slot][k]);
            atomicMax(&gmax[g * 64 + k], lmax[slot][k]);
            if (k == 0) atomicAdd(&gcnt[g], (float)lcnt[slot]);
        }
    }
}

__global__ void finalize_kernel(const float* __restrict__ gsum, const unsigned* __restrict__ gmax,
                                const float* __restrict__ gcnt, const float* __restrict__ post_w,
                                const float* __restrict__ post_b, float* __restrict__ out)
{
    const int g = blockIdx.x;
    const int k = threadIdx.x;
    const float cnt = gcnt[g];
    const float v = fdec(gmax[g * 64 + k]) + gsum[g * 64 + k] / cnt;
    const float w = post_w[k];
    float sq = v * v, dw = v * w;
    #pragma unroll
    for (int off = 32; off > 0; off >>= 1) {
        sq += __shfl_xor(sq, off, 64);
        dw += __shfl_xor(dw, off, 64);
    }
    if (k == 0) out[g] = dw / sqrtf(sq) + post_b[0];
}

extern "C" void kernel_launch(void* const* d_in, const int* in_sizes, int n_in,
                              void* d_out, int out_size, void* d_ws, size_t ws_size,
                              hipStream_t stream)
{
    const float* node_feat = (const float*)d_in[0];
    const float* cfg       = (const float*)d_in[1];
    const int*   opcode    = (const int*)  d_in[2];
    const int*   edge      = (const int*)  d_in[3];
    const int*   batch     = (const int*)  d_in[4];
    const float* op_emb    = (const float*)d_in[5];
    const float* lin_w     = (const float*)d_in[6];
    const float* lin_b     = (const float*)d_in[7];
    const float* post_w    = (const float*)d_in[8];
    const float* post_b    = (const float*)d_in[9];
    const float* pw[3] = {(const float*)d_in[10], (const float*)d_in[15], (const float*)d_in[20]};
    const float* pb[3] = {(const float*)d_in[11], (const float*)d_in[16], (const float*)d_in[21]};
    const float* wl[3] = {(const float*)d_in[12], (const float*)d_in[17], (const float*)d_in[22]};
    const float* bl[3] = {(const float*)d_in[13], (const float*)d_in[18], (const float*)d_in[23]};
    const float* wr[3] = {(const float*)d_in[14], (const float*)d_in[19], (const float*)d_in[24]};
    const int* srcp = edge;
    const int* dstp = edge + N_EDGES;

    // workspace layout (fp32-element offsets) — aliased slots, ~135 MB total
    float* ws   = (float*)d_ws;
    int*   nbr       = (int*)(ws + 32000000);  // N_EDGES
    int*   row_start = (int*)(ws + 33600000);  // N+1
    int*   cnt       = (int*)(ws + 33700064);  // N (counts -> fill cursor)
    int*   bsum      = (int*)(ws + 33800064);  // 512
    float* wpad      = ws + 33800576;          // 192*128
    float* gsum      = ws + 33825152;          // 64*64
    float* gcnt      = ws + 33829248;          // 64
    unsigned* gmax   = (unsigned*)(ws + 33829312); // 64*64

    // float-region lifetimes [0, 32M floats):
    unsigned short* A_bf    = (unsigned short*)ws;              // [0,6.4M) N x 128 bf16; dead after r0
    unsigned short* C2_bf   = (unsigned short*)ws;              // [0,3.2M) over dead A (combine1 out)
    float*          C3      = ws;                               // [0,6.4M) over dead C2 (combine2 out)
    unsigned short* C1_bf   = (unsigned short*)(ws + 6400000);  // [6.4M,9.6M) combine0 out
    unsigned short* X0_bf   = (unsigned short*)(ws + 12800000); // [12.8M,22.4M) N x 192 bf16; dead after embed
    unsigned short* xp128_bf= (unsigned short*)(ws + 12800000); // [12.8M,19.2M) N x 128 bf16; dead after yp0
    float*          xp64    = ws + 12800000;                    // [12.8M,19.2M) N x 64 fp32 (layers 1/2)
    float*          r       = ws + 19200000;                    // [19.2M,25.6M) N x 64 fp32 root term
    unsigned short* yp      = (unsigned short*)(ws + 25600000); // [25.6M,28.8M) N x 64 bf16

    hipMemsetAsync(cnt, 0, (size_t)N_NODES * 4, stream);
    hipMemsetAsync(gsum, 0, (size_t)(4096 + 64 + 4096) * 4, stream);

    // ---- CSR build (by dst) ----
    hist_kernel<<<(N_EDGES + 255) / 256, 256, 0, stream>>>(dstp, cnt);
    blocksum_kernel<<<NB_SCAN, 256, 0, stream>>>(cnt, bsum);
    scanbsum_kernel<<<1, 512, 0, stream>>>(bsum);
    offsets_kernel<<<NB_SCAN, 256, 0, stream>>>(cnt, bsum, row_start);
    fill_kernel<<<8 * 104, 256, 0, stream>>>(srcp, dstp, cnt, nbr);

    // ---- embed: X0 = concat(bf16); A = relu(X0 @ wpad + lin_b) (bf16) ----
    concat_kernel<<<4096, 256, 0, stream>>>(node_feat, cfg, opcode, op_emb, X0_bf);
    wpad_kernel<<<(K_EMB * 128 + 255) / 256, 256, 0, stream>>>(lin_w, wpad);
    gemm_kernel<128, 64, true, true, true, true><<<dim3(391, 2), 256, 0, stream>>>(
        X0_bf, K_EMB, K_EMB, wpad, lin_b, A_bf, N_NODES);

    // ---- layer 0 (D=128) ----
    gemm_kernel<128, 64, true,  true,  true,  true ><<<dim3(391, 2), 256, 0, stream>>>(
        A_bf, 128, 128, pw[0], pb[0], xp128_bf, N_NODES);
    gemm_kernel< 64, 64, false, false, true,  true ><<<dim3(391, 1), 256, 0, stream>>>(
        xp128_bf, 128, 128, wl[0], nullptr, yp, N_NODES);
    gemm_kernel< 64, 64, true,  false, false, true ><<<dim3(391, 1), 256, 0, stream>>>(
        A_bf, 128, 128, wr[0], bl[0], r, N_NODES);
    combine_kernel<true><<<2048, 256, 0, stream>>>(row_start, nbr, yp, r, C1_bf);

    // ---- layer 1 (D=64) ----
    gemm_kernel< 64, 64, true,  true,  false, true ><<<dim3(391, 1), 256, 0, stream>>>(
        C1_bf, 64, 64, pw[1], pb[1], xp64, N_NODES);
    gemm_kernel< 64, 64, false, false, true,  false><<<dim3(391, 1), 256, 0, stream>>>(
        xp64, 64, 64, wl[1], nullptr, yp, N_NODES);
    gemm_kernel< 64, 64, true,  false, false, true ><<<dim3(391, 1), 256, 0, stream>>>(
        C1_bf, 64, 64, wr[1], bl[1], r, N_NODES);
    combine_kernel<true><<<2048, 256, 0, stream>>>(row_start, nbr, yp, r, C2_bf);

    // ---- layer 2 (D=64) ----
    gemm_kernel< 64, 64, true,  true,  false, true ><<<dim3(391, 1), 256, 0, stream>>>(
        C2_bf, 64, 64, pw[2], pb[2], xp64, N_NODES);
    gemm_kernel< 64, 64, false, false, true,  false><<<dim3(391, 1), 256, 0, stream>>>(
        xp64, 64, 64, wl[2], nullptr, yp, N_NODES);
    gemm_kernel< 64, 64, true,  false, false, true ><<<dim3(391, 1), 256, 0, stream>>>(
        C2_bf, 64, 64, wr[2], bl[2], r, N_NODES);
    combine_kernel<false><<<2048, 256, 0, stream>>>(row_start, nbr, yp, r, C3);

    // ---- pooling + head ----
    pool_kernel<<<NB_SCAN, 256, 0, stream>>>(C3, batch, gsum, gmax, gcnt);
    finalize_kernel<<<N_GRAPHS, 64, 0, stream>>>(gsum, gmax, gcnt, post_w, post_b,
                                                 (float*)d_out);
}

// Round 12
// 852.503 us; speedup vs baseline: 1.2810x; 1.2810x over previous
//
#include <hip/hip_runtime.h>
#include <hip/hip_bf16.h>
#include <math.h>

#define N_NODES   100000
#define N_EDGES   1600000
#define N_GRAPHS  64
#define NF_D      140
#define OP_EMB_D  32
#define CFG_D     18
#define K_EMB     192     // 190 zero-padded to 192
#define NB_SCAN   391     // ceil(N_NODES/256)
#define NTILES    1563    // ceil(N_NODES/64)
#define NGROUPS   391     // ceil(NTILES/4) — 4 node-tiles (waves) per block

// monotone float<->uint encoding for atomicMax on floats
__device__ __forceinline__ unsigned fenc(float f) {
    unsigned u = __float_as_uint(f);
    return (u & 0x80000000u) ? ~u : (u | 0x80000000u);
}
__device__ __forceinline__ float fdec(unsigned u) {
    unsigned v = (u & 0x80000000u) ? (u & 0x7FFFFFFFu) : ~u;
    return __uint_as_float(v);
}
// self-contained bf16 pack/unpack (RNE; finite inputs only)
__device__ __forceinline__ unsigned short f2bf(float f) {
    unsigned u = __float_as_uint(f);
    return (unsigned short)((u + 0x7FFFu + ((u >> 16) & 1u)) >> 16);
}
__device__ __forceinline__ float bf2f(unsigned short h) {
    return __uint_as_float((unsigned)h << 16);
}

// ---------------- CSR build ----------------

__global__ void hist_kernel(const int* __restrict__ dst, int* __restrict__ cnt) {
    int e = blockIdx.x * blockDim.x + threadIdx.x;
    if (e < N_EDGES) atomicAdd(&cnt[dst[e]], 1);
}

__global__ __launch_bounds__(256) void blocksum_kernel(const int* __restrict__ cnt,
                                                       int* __restrict__ bsum) {
    const int tid = threadIdx.x, lane = tid & 63, wave = tid >> 6;
    int i = blockIdx.x * 256 + tid;
    int v = (i < N_NODES) ? cnt[i] : 0;
    #pragma unroll
    for (int off = 32; off > 0; off >>= 1) v += __shfl_xor(v, off, 64);
    __shared__ int wsum[4];
    if (lane == 0) wsum[wave] = v;
    __syncthreads();
    if (tid == 0) bsum[blockIdx.x] = wsum[0] + wsum[1] + wsum[2] + wsum[3];
}

__global__ __launch_bounds__(512) void scanbsum_kernel(int* __restrict__ bsum) {
    __shared__ int s[512];
    const int t = threadIdx.x;
    int v0 = (t < NB_SCAN) ? bsum[t] : 0;
    s[t] = v0;
    __syncthreads();
    for (int off = 1; off < 512; off <<= 1) {
        int add = (t >= off) ? s[t - off] : 0;
        __syncthreads();
        s[t] += add;
        __syncthreads();
    }
    if (t < NB_SCAN) bsum[t] = s[t] - v0;   // exclusive
}

__global__ __launch_bounds__(256) void offsets_kernel(int* __restrict__ cnt,
                                                      const int* __restrict__ bsum,
                                                      int* __restrict__ row_start) {
    const int t = threadIdx.x;
    const int i = blockIdx.x * 256 + t;
    int v0 = (i < N_NODES) ? cnt[i] : 0;
    __shared__ int s[256];
    s[t] = v0;
    __syncthreads();
    for (int off = 1; off < 256; off <<= 1) {
        int add = (t >= off) ? s[t - off] : 0;
        __syncthreads();
        s[t] += add;
        __syncthreads();
    }
    const int excl = s[t] - v0 + bsum[blockIdx.x];
    if (i < N_NODES) {
        row_start[i] = excl;
        cnt[i] = excl;                 // becomes the fill cursor
    }
    if (i == N_NODES - 1) row_start[N_NODES] = excl + v0;  // == N_EDGES
}

// range-partitioned fill (R7: random scatter caused 16x write amp; this keeps
// each 0.8MB nbr slice hot in one XCD L2 via the blockIdx%8 heuristic).
__global__ void fill_kernel(const int* __restrict__ src, const int* __restrict__ dst,
                            int* __restrict__ cursor, int* __restrict__ nbr) {
    const int range = blockIdx.x & 7;
    const int lo = range * (N_NODES / 8);
    const int hi = lo + (N_NODES / 8);
    const int groups = gridDim.x >> 3;
    const int sub = blockIdx.x >> 3;
    for (int e = sub * blockDim.x + threadIdx.x; e < N_EDGES;
         e += groups * blockDim.x) {
        const int d = dst[e];
        if (d >= lo && d < hi) {
            const int slot = atomicAdd(&cursor[d], 1);
            nbr[slot] = src[e];
        }
    }
}

// ---------------- input concat (bf16 out) + weight pad ----------------

__global__ __launch_bounds__(256) void concat_kernel(
    const float* __restrict__ node_feat, const float* __restrict__ cfg,
    const int* __restrict__ opcode, const float* __restrict__ op_emb,
    unsigned short* __restrict__ x0)
{
    const long long total = (long long)N_NODES * 96;   // 2-col units
    for (long long idx = (long long)blockIdx.x * blockDim.x + threadIdx.x;
         idx < total; idx += (long long)gridDim.x * blockDim.x) {
        const int n  = (int)(idx / 96);
        const int c  = 2 * (int)(idx % 96);
        float2 v;
        if (c < NF_D) {
            v = *(const float2*)(node_feat + (long long)n * NF_D + c);
        } else if (c < NF_D + OP_EMB_D) {
            const int op = opcode[n];
            v = *(const float2*)(op_emb + op * OP_EMB_D + (c - NF_D));
        } else if (c < 190) {
            v = *(const float2*)(cfg + (long long)n * CFG_D + (c - NF_D - OP_EMB_D));
        } else {
            v.x = 0.f; v.y = 0.f;
        }
        const unsigned pk = ((unsigned)f2bf(v.y) << 16) | (unsigned)f2bf(v.x);
        *(unsigned*)(x0 + (long long)n * K_EMB + c) = pk;
    }
}

__global__ void wpad_kernel(const float* __restrict__ w, float* __restrict__ wp) {
    int i = blockIdx.x * blockDim.x + threadIdx.x;
    if (i < K_EMB * 128) wp[i] = (i < 190 * 128) ? w[i] : 0.f;
}

// ---------------- lane-per-node GEMM (wave-local staging, NO barriers — R9 lesson) ----------------
// wave = 64-node tile, lane = node. NY = M/32 col-tiles of 32 (acc[32] — R11's
// JW=64 blew the SGPR prefetch budget AND starved small-GEMM TLP).
// XCD-coherent mapping: blockIdx.x = xcd + 8*(jh + NY*ghi), g = ghi*8 + xcd —
// all NY col-tiles of a node-group land 8 apart (same XCD slot, adjacent in
// dispatch) so they share the input tile in that XCD's L2 and merge their 64B
// output chunks into full lines (R10/R11: dim3(x,y) gave them zero L2 overlap).
// IBF16: bf16 input staged via uint4 + register unpack into fp32 LDS.
// OBF16: bf16 output rows. Weights fp32, wave-uniform -> s_load.
template <int M, bool BIAS, bool RELU, bool OBF16, bool IBF16>
__global__ __launch_bounds__(256) void gemm_kernel(
    const void* __restrict__ xin, int SX, int K,
    const float* __restrict__ w, const float* __restrict__ b,
    void* __restrict__ outv, int N)
{
    constexpr int NY = M / 32;
    __shared__ float sx[4][64][36];
    const int tid = threadIdx.x, wave = tid >> 6, lane = tid & 63;
    const int xcd = blockIdx.x & 7;
    const int q   = blockIdx.x >> 3;
    const int jh  = q % NY;
    const int g   = (q / NY) * 8 + xcd;
    if (g >= NGROUPS) return;                 // pad block (no barriers in kernel)
    const int tile = g * 4 + wave;
    if (tile >= NTILES) return;
    const int base = tile << 6;
    float acc[32];
    #pragma unroll
    for (int j = 0; j < 32; ++j) acc[j] = BIAS ? b[jh * 32 + j] : 0.f;
    for (int kc = 0; kc < K; kc += 32) {
        if (IBF16) {
            const unsigned short* x = (const unsigned short*)xin;
            const int r16 = lane >> 2, c2 = lane & 3;   // 16 rows x 4 uint4 per pass
            #pragma unroll
            for (int rt = 0; rt < 4; ++rt) {
                int row = base + rt * 16 + r16;
                if (row >= N) row = N - 1;
                uint4 u = *(const uint4*)(x + (long long)row * SX + kc + c2 * 8);
                float4 lo, hi;
                lo.x = __uint_as_float(u.x << 16);
                lo.y = __uint_as_float(u.x & 0xffff0000u);
                lo.z = __uint_as_float(u.y << 16);
                lo.w = __uint_as_float(u.y & 0xffff0000u);
                hi.x = __uint_as_float(u.z << 16);
                hi.y = __uint_as_float(u.z & 0xffff0000u);
                hi.z = __uint_as_float(u.w << 16);
                hi.w = __uint_as_float(u.w & 0xffff0000u);
                *(float4*)(&sx[wave][rt * 16 + r16][c2 * 8 + 0]) = lo;
                *(float4*)(&sx[wave][rt * 16 + r16][c2 * 8 + 4]) = hi;
            }
        } else {
            const float* x = (const float*)xin;
            const int r8 = lane >> 3, c4 = lane & 7;    // 8 rows x 8 float4 per pass
            #pragma unroll
            for (int rt = 0; rt < 8; ++rt) {
                int row = base + rt * 8 + r8;
                if (row >= N) row = N - 1;
                float4 v = *(const float4*)(x + (long long)row * SX + kc + c4 * 4);
                *(float4*)(&sx[wave][rt * 8 + r8][c4 * 4]) = v;
            }
        }
        // wave-local staging: in-order DS pipe + compiler waitcnt suffice
        #pragma unroll 2
        for (int i4 = 0; i4 < 8; ++i4) {
            float4 xv = *(const float4*)(&sx[wave][lane][i4 * 4]);
            const float* wrow = w + (long long)(kc + i4 * 4) * M + jh * 32;
            #pragma unroll
            for (int qq = 0; qq < 4; ++qq) {
                const float xq = (qq == 0) ? xv.x : (qq == 1) ? xv.y
                               : (qq == 2) ? xv.z : xv.w;
                #pragma unroll
                for (int j = 0; j < 32; ++j)
                    acc[j] = fmaf(xq, wrow[qq * M + j], acc[j]);
            }
        }
    }
    const int n = base + lane;
    if (n < N) {
        if (OBF16) {
            unsigned short* orow = (unsigned short*)outv + (long long)n * M + jh * 32;
            #pragma unroll
            for (int j8 = 0; j8 < 4; ++j8) {
                uint4 pk;
                unsigned* pu = (unsigned*)&pk;
                #pragma unroll
                for (int h = 0; h < 4; ++h) {
                    float f0 = acc[j8 * 8 + h * 2], f1 = acc[j8 * 8 + h * 2 + 1];
                    if (RELU) { f0 = fmaxf(f0, 0.f); f1 = fmaxf(f1, 0.f); }
                    pu[h] = ((unsigned)f2bf(f1) << 16) | (unsigned)f2bf(f0);
                }
                *(uint4*)(orow + j8 * 8) = pk;
            }
        } else {
            float* orow = (float*)outv + (long long)n * M + jh * 32;
            #pragma unroll
            for (int j4 = 0; j4 < 8; ++j4) {
                float4 v;
                v.x = acc[j4 * 4 + 0]; v.y = acc[j4 * 4 + 1];
                v.z = acc[j4 * 4 + 2]; v.w = acc[j4 * 4 + 3];
                if (RELU) {
                    v.x = fmaxf(v.x, 0.f); v.y = fmaxf(v.y, 0.f);
                    v.z = fmaxf(v.z, 0.f); v.w = fmaxf(v.w, 0.f);
                }
                *(float4*)(orow + j4 * 4) = v;
            }
        }
    }
}

// ---------------- gather + normalize (root term precomputed as r) ----------------
// out[n] = normalize( gather_mean(yp)[n] + r[n] ),  r = x@wr + bl (dense GEMM)
// yp bf16; fp32 accumulate. 8 waves/SIMD; 8 independent gather accumulators.
// OBF16: write the normalized output as bf16 (C1/C2 are re-read twice by GEMMs).
template <bool OBF16>
__global__ __launch_bounds__(256, 8) void combine_kernel(
    const int* __restrict__ row_start, const int* __restrict__ nbr,
    const unsigned short* __restrict__ yp, const float* __restrict__ r,
    void* __restrict__ out)
{
    const int tid = threadIdx.x, wave = tid >> 6, lane = tid & 63;
    for (int n = blockIdx.x * 4 + wave; n < N_NODES; n += gridDim.x * 4) {
        const int rs = row_start[n], re = row_start[n + 1];
        float macc[8];
        #pragma unroll
        for (int q = 0; q < 8; ++q) macc[q] = 0.f;
        for (int eb = rs; eb < re; eb += 64) {
            const int cnt = min(64, re - eb);
            const int my = (eb + lane < re) ? nbr[eb + lane] : 0;
            for (int j2 = 0; j2 < cnt; j2 += 8) {
                #pragma unroll
                for (int q = 0; q < 8; ++q) {
                    const int jj = j2 + q;                       // wave-uniform
                    const int s = __shfl(my, (jj < cnt) ? jj : 0, 64);
                    const float v = bf2f(yp[(long long)s * 64 + lane]);
                    if (jj < cnt) macc[q] += v;                  // uniform predicate
                }
            }
        }
        const float m = ((macc[0] + macc[1]) + (macc[2] + macc[3]))
                      + ((macc[4] + macc[5]) + (macc[6] + macc[7]));
        float acc = r[(long long)n * 64 + lane] + m / fmaxf((float)(re - rs), 1.0f);
        float sq = acc * acc;
        #pragma unroll
        for (int off = 32; off > 0; off >>= 1) sq += __shfl_xor(sq, off, 64);
        const float res = acc / fmaxf(sqrtf(sq), 1e-12f);
        if (OBF16)
            ((unsigned short*)out)[(long long)n * 64 + lane] = f2bf(res);
        else
            ((float*)out)[(long long)n * 64 + lane] = res;
    }
}

// ---------------- pooling (block pre-reduction) + head ----------------

__global__ __launch_bounds__(256) void pool_kernel(
    const float* __restrict__ x, const int* __restrict__ batch,
    float* __restrict__ gsum, unsigned* __restrict__ gmax, float* __restrict__ gcnt)
{
    __shared__ float    lsum[2][64];
    __shared__ unsigned lmax[2][64];
    __shared__ int      lcnt[2];
    const int tid = threadIdx.x, wave = tid >> 6, lane = tid & 63;
    if (tid < 128) { lsum[tid >> 6][tid & 63] = 0.f; lmax[tid >> 6][tid & 63] = 0u; }
    if (tid < 2) lcnt[tid] = 0;
    __syncthreads();
    const int base = blockIdx.x * 256;
    const int g0 = batch[base];
    float a0 = 0.f, a1 = 0.f, x0 = -INFINITY, x1 = -INFINITY;
    int c0 = 0, c1 = 0;
    for (int nn = 0; nn < 64; ++nn) {
        const int n = base + wave * 64 + nn;
        if (n >= N_NODES) break;
        const float v = x[(long long)n * 64 + lane];
        const int slot = batch[n] - g0;
        if (slot == 0)      { a0 += v; x0 = fmaxf(x0, v); c0++; }
        else if (slot == 1) { a1 += v; x1 = fmaxf(x1, v); c1++; }
        else {
            const int g = g0 + slot;
            atomicAdd(&gsum[g * 64 + lane], v);
            atomicMax(&gmax[g * 64 + lane], fenc(v));
            if (lane == 0) atomicAdd(&gcnt[g], 1.f);
        }
    }
    if (c0) { atomicAdd(&lsum[0][lane], a0); atomicMax(&lmax[0][lane], fenc(x0));
              if (lane == 0) atomicAdd(&lcnt[0], c0); }
    if (c1) { atomicAdd(&lsum[1][lane], a1); atomicMax(&lmax[1][lane], fenc(x1));
              if (lane == 0) atomicAdd(&lcnt[1], c1); }
    __syncthreads();
    if (tid < 128) {
        const int slot = tid >> 6, k = tid & 63;
        if (lcnt[slot] > 0) {
            const int g = g0 + slot;
            atomicAdd(&gsum[g * 64 + k], lsum[slot][k]);
            atomicMax(&gmax[g * 64 + k], lmax[slot][k]);
            if (k == 0) atomicAdd(&gcnt[g], (float)lcnt[slot]);
        }
    }
}

__global__ void finalize_kernel(const float* __restrict__ gsum, const unsigned* __restrict__ gmax,
                                const float* __restrict__ gcnt, const float* __restrict__ post_w,
                                const float* __restrict__ post_b, float* __restrict__ out)
{
    const int g = blockIdx.x;
    const int k = threadIdx.x;
    const float cnt = gcnt[g];
    const float v = fdec(gmax[g * 64 + k]) + gsum[g * 64 + k] / cnt;
    const float w = post_w[k];
    float sq = v * v, dw = v * w;
    #pragma unroll
    for (int off = 32; off > 0; off >>= 1) {
        sq += __shfl_xor(sq, off, 64);
        dw += __shfl_xor(dw, off, 64);
    }
    if (k == 0) out[g] = dw / sqrtf(sq) + post_b[0];
}

extern "C" void kernel_launch(void* const* d_in, const int* in_sizes, int n_in,
                              void* d_out, int out_size, void* d_ws, size_t ws_size,
                              hipStream_t stream)
{
    const float* node_feat = (const float*)d_in[0];
    const float* cfg       = (const float*)d_in[1];
    const int*   opcode    = (const int*)  d_in[2];
    const int*   edge      = (const int*)  d_in[3];
    const int*   batch     = (const int*)  d_in[4];
    const float* op_emb    = (const float*)d_in[5];
    const float* lin_w     = (const float*)d_in[6];
    const float* lin_b     = (const float*)d_in[7];
    const float* post_w    = (const float*)d_in[8];
    const float* post_b    = (const float*)d_in[9];
    const float* pw[3] = {(const float*)d_in[10], (const float*)d_in[15], (const float*)d_in[20]};
    const float* pb[3] = {(const float*)d_in[11], (const float*)d_in[16], (const float*)d_in[21]};
    const float* wl[3] = {(const float*)d_in[12], (const float*)d_in[17], (const float*)d_in[22]};
    const float* bl[3] = {(const float*)d_in[13], (const float*)d_in[18], (const float*)d_in[23]};
    const float* wr[3] = {(const float*)d_in[14], (const float*)d_in[19], (const float*)d_in[24]};
    const int* srcp = edge;
    const int* dstp = edge + N_EDGES;

    // workspace layout (fp32-element offsets) — aliased slots, ~135 MB total
    float* ws   = (float*)d_ws;
    int*   nbr       = (int*)(ws + 32000000);  // N_EDGES
    int*   row_start = (int*)(ws + 33600000);  // N+1
    int*   cnt       = (int*)(ws + 33700064);  // N (counts -> fill cursor)
    int*   bsum      = (int*)(ws + 33800064);  // 512
    float* wpad      = ws + 33800576;          // 192*128
    float* gsum      = ws + 33825152;          // 64*64
    float* gcnt      = ws + 33829248;          // 64
    unsigned* gmax   = (unsigned*)(ws + 33829312); // 64*64

    // float-region lifetimes [0, 32M floats):
    unsigned short* A_bf    = (unsigned short*)ws;              // [0,6.4M) N x 128 bf16; dead after r0
    unsigned short* C2_bf   = (unsigned short*)ws;              // [0,3.2M) over dead A (combine1 out)
    float*          C3      = ws;                               // [0,6.4M) over dead C2 (combine2 out)
    unsigned short* C1_bf   = (unsigned short*)(ws + 6400000);  // [6.4M,9.6M) combine0 out
    unsigned short* X0_bf   = (unsigned short*)(ws + 12800000); // [12.8M,22.4M) N x 192 bf16; dead after embed
    unsigned short* xp128_bf= (unsigned short*)(ws + 12800000); // [12.8M,19.2M) N x 128 bf16; dead after yp0
    float*          xp64    = ws + 12800000;                    // [12.8M,19.2M) N x 64 fp32 (layers 1/2)
    float*          r       = ws + 19200000;                    // [19.2M,25.6M) N x 64 fp32 root term
    unsigned short* yp      = (unsigned short*)(ws + 25600000); // [25.6M,28.8M) N x 64 bf16

    hipMemsetAsync(cnt, 0, (size_t)N_NODES * 4, stream);
    hipMemsetAsync(gsum, 0, (size_t)(4096 + 64 + 4096) * 4, stream);

    // ---- CSR build (by dst) ----
    hist_kernel<<<(N_EDGES + 255) / 256, 256, 0, stream>>>(dstp, cnt);
    blocksum_kernel<<<NB_SCAN, 256, 0, stream>>>(cnt, bsum);
    scanbsum_kernel<<<1, 512, 0, stream>>>(bsum);
    offsets_kernel<<<NB_SCAN, 256, 0, stream>>>(cnt, bsum, row_start);
    fill_kernel<<<8 * 104, 256, 0, stream>>>(srcp, dstp, cnt, nbr);

    // XCD-swizzled grids: 8 * NY * ceil(NGROUPS/8) blocks
    const int GRID128 = 8 * 4 * ((NGROUPS + 7) / 8);   // 1568
    const int GRID64  = 8 * 2 * ((NGROUPS + 7) / 8);   // 784

    // ---- embed: X0 = concat(bf16); A = relu(X0 @ wpad + lin_b) (bf16) ----
    concat_kernel<<<4096, 256, 0, stream>>>(node_feat, cfg, opcode, op_emb, X0_bf);
    wpad_kernel<<<(K_EMB * 128 + 255) / 256, 256, 0, stream>>>(lin_w, wpad);
    gemm_kernel<128, true, true, true, true><<<GRID128, 256, 0, stream>>>(
        X0_bf, K_EMB, K_EMB, wpad, lin_b, A_bf, N_NODES);

    // ---- layer 0 (D=128) ----
    gemm_kernel<128, true,  true,  true,  true ><<<GRID128, 256, 0, stream>>>(
        A_bf, 128, 128, pw[0], pb[0], xp128_bf, N_NODES);
    gemm_kernel< 64, false, false, true,  true ><<<GRID64, 256, 0, stream>>>(
        xp128_bf, 128, 128, wl[0], nullptr, yp, N_NODES);
    gemm_kernel< 64, true,  false, false, true ><<<GRID64, 256, 0, stream>>>(
        A_bf, 128, 128, wr[0], bl[0], r, N_NODES);
    combine_kernel<true><<<2048, 256, 0, stream>>>(row_start, nbr, yp, r, C1_bf);

    // ---- layer 1 (D=64) ----
    gemm_kernel< 64, true,  true,  false, true ><<<GRID64, 256, 0, stream>>>(
        C1_bf, 64, 64, pw[1], pb[1], xp64, N_NODES);
    gemm_kernel< 64, false, false, true,  false><<<GRID64, 256, 0, stream>>>(
        xp64, 64, 64, wl[1], nullptr, yp, N_NODES);
    gemm_kernel< 64, true,  false, false, true ><<<GRID64, 256, 0, stream>>>(
        C1_bf, 64, 64, wr[1], bl[1], r, N_NODES);
    combine_kernel<true><<<2048, 256, 0, stream>>>(row_start, nbr, yp, r, C2_bf);

    // ---- layer 2 (D=64) ----
    gemm_kernel< 64, true,  true,  false, true ><<<GRID64, 256, 0, stream>>>(
        C2_bf, 64, 64, pw[2], pb[2], xp64, N_NODES);
    gemm_kernel< 64, false, false, true,  false><<<GRID64, 256, 0, stream>>>(
        xp64, 64, 64, wl[2], nullptr, yp, N_NODES);
    gemm_kernel< 64, true,  false, false, true ><<<GRID64, 256, 0, stream>>>(
        C2_bf, 64, 64, wr[2], bl[2], r, N_NODES);
    combine_kernel<false><<<2048, 256, 0, stream>>>(row_start, nbr, yp, r, C3);

    // ---- pooling + head ----
    pool_kernel<<<NB_SCAN, 256, 0, stream>>>(C3, batch, gsum, gmax, gcnt);
    finalize_kernel<<<N_GRAPHS, 64, 0, stream>>>(gsum, gmax, gcnt, post_w, post_b,
                                                 (float*)d_out);
}

// Round 13
// 661.073 us; speedup vs baseline: 1.6519x; 1.2896x over previous
//
#include <hip/hip_runtime.h>
#include <hip/hip_bf16.h>
#include <math.h>

#define N_NODES   100000
#define N_EDGES   1600000
#define N_GRAPHS  64
#define NF_D      140
#define OP_EMB_D  32
#define CFG_D     18
#define K_EMB     192     // 190 zero-padded to 192
#define NB_SCAN   391     // ceil(N_NODES/256)

typedef __attribute__((ext_vector_type(8))) short short8;   // 8 bf16 = 4 VGPRs
typedef __attribute__((ext_vector_type(4))) float f32x4;    // MFMA C/D frag

// monotone float<->uint encoding for atomicMax on floats
__device__ __forceinline__ unsigned fenc(float f) {
    unsigned u = __float_as_uint(f);
    return (u & 0x80000000u) ? ~u : (u | 0x80000000u);
}
__device__ __forceinline__ float fdec(unsigned u) {
    unsigned v = (u & 0x80000000u) ? (u & 0x7FFFFFFFu) : ~u;
    return __uint_as_float(v);
}
// self-contained bf16 pack/unpack (RNE; finite inputs only)
__device__ __forceinline__ unsigned short f2bf(float f) {
    unsigned u = __float_as_uint(f);
    return (unsigned short)((u + 0x7FFFu + ((u >> 16) & 1u)) >> 16);
}
__device__ __forceinline__ float bf2f(unsigned short h) {
    return __uint_as_float((unsigned)h << 16);
}
__device__ __forceinline__ short8 ld_frag(const unsigned short* p) {
    union { uint4 u; short8 s; } c;
    c.u = *(const uint4*)p;
    return c.s;
}

// ---------------- CSR build ----------------

__global__ void hist_kernel(const int* __restrict__ dst, int* __restrict__ cnt) {
    int e = blockIdx.x * blockDim.x + threadIdx.x;
    if (e < N_EDGES) atomicAdd(&cnt[dst[e]], 1);
}

__global__ __launch_bounds__(256) void blocksum_kernel(const int* __restrict__ cnt,
                                                       int* __restrict__ bsum) {
    const int tid = threadIdx.x, lane = tid & 63, wave = tid >> 6;
    int i = blockIdx.x * 256 + tid;
    int v = (i < N_NODES) ? cnt[i] : 0;
    #pragma unroll
    for (int off = 32; off > 0; off >>= 1) v += __shfl_xor(v, off, 64);
    __shared__ int wsum[4];
    if (lane == 0) wsum[wave] = v;
    __syncthreads();
    if (tid == 0) bsum[blockIdx.x] = wsum[0] + wsum[1] + wsum[2] + wsum[3];
}

__global__ __launch_bounds__(512) void scanbsum_kernel(int* __restrict__ bsum) {
    __shared__ int s[512];
    const int t = threadIdx.x;
    int v0 = (t < NB_SCAN) ? bsum[t] : 0;
    s[t] = v0;
    __syncthreads();
    for (int off = 1; off < 512; off <<= 1) {
        int add = (t >= off) ? s[t - off] : 0;
        __syncthreads();
        s[t] += add;
        __syncthreads();
    }
    if (t < NB_SCAN) bsum[t] = s[t] - v0;   // exclusive
}

__global__ __launch_bounds__(256) void offsets_kernel(int* __restrict__ cnt,
                                                      const int* __restrict__ bsum,
                                                      int* __restrict__ row_start) {
    const int t = threadIdx.x;
    const int i = blockIdx.x * 256 + t;
    int v0 = (i < N_NODES) ? cnt[i] : 0;
    __shared__ int s[256];
    s[t] = v0;
    __syncthreads();
    for (int off = 1; off < 256; off <<= 1) {
        int add = (t >= off) ? s[t - off] : 0;
        __syncthreads();
        s[t] += add;
        __syncthreads();
    }
    const int excl = s[t] - v0 + bsum[blockIdx.x];
    if (i < N_NODES) {
        row_start[i] = excl;
        cnt[i] = excl;                 // becomes the fill cursor
    }
    if (i == N_NODES - 1) row_start[N_NODES] = excl + v0;  // == N_EDGES
}

// range-partitioned fill (R7: random scatter caused 16x write amp; keeps each
// 0.8MB nbr slice hot in one XCD L2 via the blockIdx%8 heuristic).
__global__ void fill_kernel(const int* __restrict__ src, const int* __restrict__ dst,
                            int* __restrict__ cursor, int* __restrict__ nbr) {
    const int range = blockIdx.x & 7;
    const int lo = range * (N_NODES / 8);
    const int hi = lo + (N_NODES / 8);
    const int groups = gridDim.x >> 3;
    const int sub = blockIdx.x >> 3;
    for (int e = sub * blockDim.x + threadIdx.x; e < N_EDGES;
         e += groups * blockDim.x) {
        const int d = dst[e];
        if (d >= lo && d < hi) {
            const int slot = atomicAdd(&cursor[d], 1);
            nbr[slot] = src[e];
        }
    }
}

// ---------------- input concat (bf16 out) ----------------

__global__ __launch_bounds__(256) void concat_kernel(
    const float* __restrict__ node_feat, const float* __restrict__ cfg,
    const int* __restrict__ opcode, const float* __restrict__ op_emb,
    unsigned short* __restrict__ x0)
{
    const long long total = (long long)N_NODES * 96;   // 2-col units
    for (long long idx = (long long)blockIdx.x * blockDim.x + threadIdx.x;
         idx < total; idx += (long long)gridDim.x * blockDim.x) {
        const int n  = (int)(idx / 96);
        const int c  = 2 * (int)(idx % 96);
        float2 v;
        if (c < NF_D) {
            v = *(const float2*)(node_feat + (long long)n * NF_D + c);
        } else if (c < NF_D + OP_EMB_D) {
            const int op = opcode[n];
            v = *(const float2*)(op_emb + op * OP_EMB_D + (c - NF_D));
        } else if (c < 190) {
            v = *(const float2*)(cfg + (long long)n * CFG_D + (c - NF_D - OP_EMB_D));
        } else {
            v.x = 0.f; v.y = 0.f;
        }
        const unsigned pk = ((unsigned)f2bf(v.y) << 16) | (unsigned)f2bf(v.x);
        *(unsigned*)(x0 + (long long)n * K_EMB + c) = pk;
    }
}

// ---------------- weight pack: fp32 KxM -> bf16 MFMA A-frag layout ----------------
// out[r], r = kc*(M*32) + mt*512 + lane*8 + j  <-  w[k*M + m] with
// k = kc*32 + (lane>>4)*8 + j, m = mt*16 + (lane&15); rows k >= Ksrc are zero.
struct WDesc { const float* src; unsigned short* dst; int K, Ksrc, M, off; };
struct WPack { WDesc d[10]; int total; };

__global__ __launch_bounds__(256) void pack_w_kernel(WPack p) {
    const int idx = blockIdx.x * blockDim.x + threadIdx.x;
    if (idx >= p.total) return;
    #pragma unroll
    for (int i = 0; i < 10; ++i) {
        const WDesc d = p.d[i];
        if (idx >= d.off && idx < d.off + d.K * d.M) {
            const int r    = idx - d.off;
            const int kc   = r / (d.M * 32);
            const int rem  = r % (d.M * 32);
            const int mt   = rem / 512;
            const int rem2 = rem % 512;
            const int lane = rem2 >> 3;
            const int j    = rem2 & 7;
            const int k = kc * 32 + (lane >> 4) * 8 + j;
            const int m = mt * 16 + (lane & 15);
            const float v = (k < d.Ksrc) ? d.src[(long long)k * d.M + m] : 0.f;
            d.dst[r] = f2bf(v);
            return;
        }
    }
}

// ---------------- MFMA GEMM: out = act(x @ w + b), bf16 in, fp32 accum ----------------
// A-operand = packed weights (m = weight-col), B-operand = node rows
// (B[k][n]: n=lane&15 node, k=quad*8+j -> one contiguous uint4 per lane).
// D layout (m89/m91): col=lane&15 = node, row=quad*4+reg = weight-col ->
// each lane stores 4 consecutive cols per (s,mt): 8B bf16 / 16B fp32 stores.
// One wave = 32 nodes x all M cols; K fully unrolled; no LDS, no barriers.
template <int M, int K, bool BIAS, bool RELU, bool OBF16>
__global__ __launch_bounds__(256) void mfma_gemm(
    const unsigned short* __restrict__ x,
    const unsigned short* __restrict__ wpk, const float* __restrict__ b,
    void* __restrict__ outv, int N)
{
    constexpr int MT = M / 16;
    constexpr int KC = K / 32;
    const int tid = threadIdx.x, wave = tid >> 6, lane = tid & 63;
    const int wid = blockIdx.x * 4 + wave;
    if (wid >= (N >> 5)) return;                  // N % 32 == 0 (100000 = 32*3125)
    const int nb   = wid << 5;
    const int l15  = lane & 15;
    const int quad = lane >> 4;

    f32x4 acc[2][MT];
    #pragma unroll
    for (int mt = 0; mt < MT; ++mt) {
        #pragma unroll
        for (int r = 0; r < 4; ++r) {
            const float bv = BIAS ? b[mt * 16 + quad * 4 + r] : 0.f;
            acc[0][mt][r] = bv;
            acc[1][mt][r] = bv;
        }
    }
    #pragma unroll
    for (int kc = 0; kc < KC; ++kc) {
        const short8 b0 = ld_frag(x + (long long)(nb + l15)      * K + kc * 32 + quad * 8);
        const short8 b1 = ld_frag(x + (long long)(nb + 16 + l15) * K + kc * 32 + quad * 8);
        #pragma unroll
        for (int mt = 0; mt < MT; ++mt) {
            const short8 a = ld_frag(wpk + ((long long)(kc * MT + mt) * 64 + lane) * 8);
            acc[0][mt] = __builtin_amdgcn_mfma_f32_16x16x32_bf16(a, b0, acc[0][mt], 0, 0, 0);
            acc[1][mt] = __builtin_amdgcn_mfma_f32_16x16x32_bf16(a, b1, acc[1][mt], 0, 0, 0);
        }
    }
    #pragma unroll
    for (int s = 0; s < 2; ++s) {
        const long long row = nb + s * 16 + l15;
        if (OBF16) {
            unsigned short* orow = (unsigned short*)outv + row * M;
            #pragma unroll
            for (int mt = 0; mt < MT; ++mt) {
                float f0 = acc[s][mt][0], f1 = acc[s][mt][1];
                float f2 = acc[s][mt][2], f3 = acc[s][mt][3];
                if (RELU) {
                    f0 = fmaxf(f0, 0.f); f1 = fmaxf(f1, 0.f);
                    f2 = fmaxf(f2, 0.f); f3 = fmaxf(f3, 0.f);
                }
                uint2 pk;
                pk.x = ((unsigned)f2bf(f1) << 16) | (unsigned)f2bf(f0);
                pk.y = ((unsigned)f2bf(f3) << 16) | (unsigned)f2bf(f2);
                *(uint2*)(orow + mt * 16 + quad * 4) = pk;
            }
        } else {
            float* orow = (float*)outv + row * M;
            #pragma unroll
            for (int mt = 0; mt < MT; ++mt) {
                f32x4 v = acc[s][mt];
                if (RELU) {
                    v[0] = fmaxf(v[0], 0.f); v[1] = fmaxf(v[1], 0.f);
                    v[2] = fmaxf(v[2], 0.f); v[3] = fmaxf(v[3], 0.f);
                }
                *(f32x4*)(orow + mt * 16 + quad * 4) = v;
            }
        }
    }
}

// ---------------- gather + normalize (root term precomputed as r) ----------------
// out[n] = normalize( gather_mean(yp)[n] + r[n] ),  r = x@wr + bl (dense GEMM)
// yp bf16; fp32 accumulate. 8 waves/SIMD; 8 independent gather accumulators.
template <bool OBF16>
__global__ __launch_bounds__(256, 8) void combine_kernel(
    const int* __restrict__ row_start, const int* __restrict__ nbr,
    const unsigned short* __restrict__ yp, const float* __restrict__ r,
    void* __restrict__ out)
{
    const int tid = threadIdx.x, wave = tid >> 6, lane = tid & 63;
    for (int n = blockIdx.x * 4 + wave; n < N_NODES; n += gridDim.x * 4) {
        const int rs = row_start[n], re = row_start[n + 1];
        float macc[8];
        #pragma unroll
        for (int q = 0; q < 8; ++q) macc[q] = 0.f;
        for (int eb = rs; eb < re; eb += 64) {
            const int cnt = min(64, re - eb);
            const int my = (eb + lane < re) ? nbr[eb + lane] : 0;
            for (int j2 = 0; j2 < cnt; j2 += 8) {
                #pragma unroll
                for (int q = 0; q < 8; ++q) {
                    const int jj = j2 + q;                       // wave-uniform
                    const int s = __shfl(my, (jj < cnt) ? jj : 0, 64);
                    const float v = bf2f(yp[(long long)s * 64 + lane]);
                    if (jj < cnt) macc[q] += v;                  // uniform predicate
                }
            }
        }
        const float m = ((macc[0] + macc[1]) + (macc[2] + macc[3]))
                      + ((macc[4] + macc[5]) + (macc[6] + macc[7]));
        float acc = r[(long long)n * 64 + lane] + m / fmaxf((float)(re - rs), 1.0f);
        float sq = acc * acc;
        #pragma unroll
        for (int off = 32; off > 0; off >>= 1) sq += __shfl_xor(sq, off, 64);
        const float res = acc / fmaxf(sqrtf(sq), 1e-12f);
        if (OBF16)
            ((unsigned short*)out)[(long long)n * 64 + lane] = f2bf(res);
        else
            ((float*)out)[(long long)n * 64 + lane] = res;
    }
}

// ---------------- pooling (block pre-reduction) + head ----------------

__global__ __launch_bounds__(256) void pool_kernel(
    const float* __restrict__ x, const int* __restrict__ batch,
    float* __restrict__ gsum, unsigned* __restrict__ gmax, float* __restrict__ gcnt)
{
    __shared__ float    lsum[2][64];
    __shared__ unsigned lmax[2][64];
    __shared__ int      lcnt[2];
    const int tid = threadIdx.x, wave = tid >> 6, lane = tid & 63;
    if (tid < 128) { lsum[tid >> 6][tid & 63] = 0.f; lmax[tid >> 6][tid & 63] = 0u; }
    if (tid < 2) lcnt[tid] = 0;
    __syncthreads();
    const int base = blockIdx.x * 256;
    const int g0 = batch[base];
    float a0 = 0.f, a1 = 0.f, x0 = -INFINITY, x1 = -INFINITY;
    int c0 = 0, c1 = 0;
    for (int nn = 0; nn < 64; ++nn) {
        const int n = base + wave * 64 + nn;
        if (n >= N_NODES) break;
        const float v = x[(long long)n * 64 + lane];
        const int slot = batch[n] - g0;
        if (slot == 0)      { a0 += v; x0 = fmaxf(x0, v); c0++; }
        else if (slot == 1) { a1 += v; x1 = fmaxf(x1, v); c1++; }
        else {
            const int g = g0 + slot;
            atomicAdd(&gsum[g * 64 + lane], v);
            atomicMax(&gmax[g * 64 + lane], fenc(v));
            if (lane == 0) atomicAdd(&gcnt[g], 1.f);
        }
    }
    if (c0) { atomicAdd(&lsum[0][lane], a0); atomicMax(&lmax[0][lane], fenc(x0));
              if (lane == 0) atomicAdd(&lcnt[0], c0); }
    if (c1) { atomicAdd(&lsum[1][lane], a1); atomicMax(&lmax[1][lane], fenc(x1));
              if (lane == 0) atomicAdd(&lcnt[1], c1); }
    __syncthreads();
    if (tid < 128) {
        const int slot = tid >> 6, k = tid & 63;
        if (lcnt[slot] > 0) {
            const int g = g0 + slot;
            atomicAdd(&gsum[g * 64 + k], lsum[slot][k]);
            atomicMax(&gmax[g * 64 + k], lmax[slot][k]);
            if (k == 0) atomicAdd(&gcnt[g], (float)lcnt[slot]);
        }
    }
}

__global__ void finalize_kernel(const float* __restrict__ gsum, const unsigned* __restrict__ gmax,
                                const float* __restrict__ gcnt, const float* __restrict__ post_w,
                                const float* __restrict__ post_b, float* __restrict__ out)
{
    const int g = blockIdx.x;
    const int k = threadIdx.x;
    const float cnt = gcnt[g];
    const float v = fdec(gmax[g * 64 + k]) + gsum[g * 64 + k] / cnt;
    const float w = post_w[k];
    float sq = v * v, dw = v * w;
    #pragma unroll
    for (int off = 32; off > 0; off >>= 1) {
        sq += __shfl_xor(sq, off, 64);
        dw += __shfl_xor(dw, off, 64);
    }
    if (k == 0) out[g] = dw / sqrtf(sq) + post_b[0];
}

extern "C" void kernel_launch(void* const* d_in, const int* in_sizes, int n_in,
                              void* d_out, int out_size, void* d_ws, size_t ws_size,
                              hipStream_t stream)
{
    const float* node_feat = (const float*)d_in[0];
    const float* cfg       = (const float*)d_in[1];
    const int*   opcode    = (const int*)  d_in[2];
    const int*   edge      = (const int*)  d_in[3];
    const int*   batch     = (const int*)  d_in[4];
    const float* op_emb    = (const float*)d_in[5];
    const float* lin_w     = (const float*)d_in[6];
    const float* lin_b     = (const float*)d_in[7];
    const float* post_w    = (const float*)d_in[8];
    const float* post_b    = (const float*)d_in[9];
    const float* pw[3] = {(const float*)d_in[10], (const float*)d_in[15], (const float*)d_in[20]};
    const float* pb[3] = {(const float*)d_in[11], (const float*)d_in[16], (const float*)d_in[21]};
    const float* wl[3] = {(const float*)d_in[12], (const float*)d_in[17], (const float*)d_in[22]};
    const float* bl[3] = {(const float*)d_in[13], (const float*)d_in[18], (const float*)d_in[23]};
    const float* wr[3] = {(const float*)d_in[14], (const float*)d_in[19], (const float*)d_in[24]};
    const int* srcp = edge;
    const int* dstp = edge + N_EDGES;

    // workspace layout (fp32-element offsets) — R2/R3 used ~154 MB, so <=154 MB is safe
    float* ws   = (float*)d_ws;
    int*   nbr       = (int*)(ws + 32000000);  // N_EDGES
    int*   row_start = (int*)(ws + 33600000);  // N+1
    int*   cnt       = (int*)(ws + 33700064);  // N (counts -> fill cursor)
    int*   bsum      = (int*)(ws + 33800064);  // 512
    float* gsum      = ws + 33825152;          // 64*64
    float* gcnt      = ws + 33829248;          // 64
    unsigned* gmax   = (unsigned*)(ws + 33829312); // 64*64
    unsigned short* wpk_base = (unsigned short*)(ws + 34000000); // 81920 bf16 packed weights

    // packed-weight segment offsets (elements)
    const int OFF_EMB = 0;                  // 192x128
    const int OFF_PW0 = 24576;              // 128x128
    const int OFF_WL0 = 24576 + 16384;      // 128x64
    const int OFF_WR0 = OFF_WL0 + 8192;     // 128x64
    const int OFF_PW1 = OFF_WR0 + 8192;     // 64x64
    const int OFF_WL1 = OFF_PW1 + 4096;
    const int OFF_WR1 = OFF_WL1 + 4096;
    const int OFF_PW2 = OFF_WR1 + 4096;
    const int OFF_WL2 = OFF_PW2 + 4096;
    const int OFF_WR2 = OFF_WL2 + 4096;
    const int W_TOTAL = OFF_WR2 + 4096;     // 81920

    // float-region lifetimes [0, 32M floats):
    unsigned short* A_bf    = (unsigned short*)ws;              // [0,6.4M) N x 128 bf16; dead after r0
    unsigned short* C2_bf   = (unsigned short*)ws;              // [0,3.2M) over dead A (combine1 out)
    float*          C3      = ws;                               // [0,6.4M) over dead C2 (combine2 out)
    unsigned short* C1_bf   = (unsigned short*)(ws + 6400000);  // [6.4M,9.6M) combine0 out
    unsigned short* X0_bf   = (unsigned short*)(ws + 12800000); // [12.8M,22.4M) N x 192 bf16; dead after embed
    unsigned short* xp128_bf= (unsigned short*)(ws + 12800000); // [12.8M,19.2M) N x 128 bf16; dead after yp0
    unsigned short* xp64_bf = (unsigned short*)(ws + 12800000); // [12.8M,16M) N x 64 bf16 (layers 1/2)
    float*          r       = ws + 19200000;                    // [19.2M,25.6M) N x 64 fp32 root term
    unsigned short* yp      = (unsigned short*)(ws + 25600000); // [25.6M,28.8M) N x 64 bf16

    hipMemsetAsync(cnt, 0, (size_t)N_NODES * 4, stream);
    hipMemsetAsync(gsum, 0, (size_t)(4096 + 64 + 4096) * 4, stream);

    // ---- pack all weights to bf16 MFMA A-frag layout (one tiny kernel) ----
    WPack wp;
    wp.d[0] = { lin_w, wpk_base + OFF_EMB, K_EMB, 190, 128, OFF_EMB };
    wp.d[1] = { pw[0], wpk_base + OFF_PW0, 128, 128, 128, OFF_PW0 };
    wp.d[2] = { wl[0], wpk_base + OFF_WL0, 128, 128,  64, OFF_WL0 };
    wp.d[3] = { wr[0], wpk_base + OFF_WR0, 128, 128,  64, OFF_WR0 };
    wp.d[4] = { pw[1], wpk_base + OFF_PW1,  64,  64,  64, OFF_PW1 };
    wp.d[5] = { wl[1], wpk_base + OFF_WL1,  64,  64,  64, OFF_WL1 };
    wp.d[6] = { wr[1], wpk_base + OFF_WR1,  64,  64,  64, OFF_WR1 };
    wp.d[7] = { pw[2], wpk_base + OFF_PW2,  64,  64,  64, OFF_PW2 };
    wp.d[8] = { wl[2], wpk_base + OFF_WL2,  64,  64,  64, OFF_WL2 };
    wp.d[9] = { wr[2], wpk_base + OFF_WR2,  64,  64,  64, OFF_WR2 };
    wp.total = W_TOTAL;
    pack_w_kernel<<<(W_TOTAL + 255) / 256, 256, 0, stream>>>(wp);

    // ---- CSR build (by dst) ----
    hist_kernel<<<(N_EDGES + 255) / 256, 256, 0, stream>>>(dstp, cnt);
    blocksum_kernel<<<NB_SCAN, 256, 0, stream>>>(cnt, bsum);
    scanbsum_kernel<<<1, 512, 0, stream>>>(bsum);
    offsets_kernel<<<NB_SCAN, 256, 0, stream>>>(cnt, bsum, row_start);
    fill_kernel<<<8 * 104, 256, 0, stream>>>(srcp, dstp, cnt, nbr);

    // ---- embed ----
    concat_kernel<<<4096, 256, 0, stream>>>(node_feat, cfg, opcode, op_emb, X0_bf);

    const int GW = (N_NODES / 32 + 3) / 4;   // 782 blocks (3125 waves)

    mfma_gemm<128, 192, true, true, true><<<GW, 256, 0, stream>>>(
        X0_bf, wpk_base + OFF_EMB, lin_b, A_bf, N_NODES);

    // ---- layer 0 (D=128) ----
    mfma_gemm<128, 128, true,  true,  true ><<<GW, 256, 0, stream>>>(
        A_bf, wpk_base + OFF_PW0, pb[0], xp128_bf, N_NODES);
    mfma_gemm< 64, 128, false, false, true ><<<GW, 256, 0, stream>>>(
        xp128_bf, wpk_base + OFF_WL0, nullptr, yp, N_NODES);
    mfma_gemm< 64, 128, true,  false, false><<<GW, 256, 0, stream>>>(
        A_bf, wpk_base + OFF_WR0, bl[0], r, N_NODES);
    combine_kernel<true><<<2048, 256, 0, stream>>>(row_start, nbr, yp, r, C1_bf);

    // ---- layer 1 (D=64) ----
    mfma_gemm< 64, 64, true,  true,  true ><<<GW, 256, 0, stream>>>(
        C1_bf, wpk_base + OFF_PW1, pb[1], xp64_bf, N_NODES);
    mfma_gemm< 64, 64, false, false, true ><<<GW, 256, 0, stream>>>(
        xp64_bf, wpk_base + OFF_WL1, nullptr, yp, N_NODES);
    mfma_gemm< 64, 64, true,  false, false><<<GW, 256, 0, stream>>>(
        C1_bf, wpk_base + OFF_WR1, bl[1], r, N_NODES);
    combine_kernel<true><<<2048, 256, 0, stream>>>(row_start, nbr, yp, r, C2_bf);

    // ---- layer 2 (D=64) ----
    mfma_gemm< 64, 64, true,  true,  true ><<<GW, 256, 0, stream>>>(
        C2_bf, wpk_base + OFF_PW2, pb[2], xp64_bf, N_NODES);
    mfma_gemm< 64, 64, false, false, true ><<<GW, 256, 0, stream>>>(
        xp64_bf, wpk_base + OFF_WL2, nullptr, yp, N_NODES);
    mfma_gemm< 64, 64, true,  false, false><<<GW, 256, 0, stream>>>(
        C2_bf, wpk_base + OFF_WR2, bl[2], r, N_NODES);
    combine_kernel<false><<<2048, 256, 0, stream>>>(row_start, nbr, yp, r, C3);

    // ---- pooling + head ----
    pool_kernel<<<NB_SCAN, 256, 0, stream>>>(C3, batch, gsum, gmax, gcnt);
    finalize_kernel<<<N_GRAPHS, 64, 0, stream>>>(gsum, gmax, gcnt, post_w, post_b,
                                                 (float*)d_out);
}